// Round 2
// baseline (277.039 us; speedup 1.0000x reference)
//
#include <hip/hip_runtime.h>
#include <hip/hip_bf16.h>

// out[i][d] = params[idx[i]] * xs[i][d];  N=4194304, D=8, V=1048576
// Latency-bound gather-scale -> K=8 unrolled grid-stride for MLP.
// Non-temporal on streaming xs/idx/out to keep params table L2-resident.

typedef float f4 __attribute__((ext_vector_type(4)));

#define K_UNROLL 8

__global__ __launch_bounds__(256) void spvar_kernel(
    const f4*    __restrict__ xs4,
    const int*   __restrict__ idx,
    const float* __restrict__ params,
    f4*          __restrict__ out4,
    int stride)   // stride = n4 / K_UNROLL; grid*block == stride exactly
{
    int tid = blockIdx.x * blockDim.x + threadIdx.x;

    // 8 independent idx loads (2 adjacent lanes share a value; cache-broadcast)
    int id[K_UNROLL];
#pragma unroll
    for (int k = 0; k < K_UNROLL; ++k) {
        int i = tid + k * stride;
        id[k] = __builtin_nontemporal_load(&idx[i >> 1]);   // D=8 -> 2 f4/row
    }

    // 8 independent random gathers into the 4 MiB params table (L2-cached)
    float p[K_UNROLL];
#pragma unroll
    for (int k = 0; k < K_UNROLL; ++k)
        p[k] = params[id[k]];

    // 8 independent streaming xs loads, perfectly coalesced per instruction
    f4 x[K_UNROLL];
#pragma unroll
    for (int k = 0; k < K_UNROLL; ++k)
        x[k] = __builtin_nontemporal_load(&xs4[tid + k * stride]);

#pragma unroll
    for (int k = 0; k < K_UNROLL; ++k) {
        f4 o = x[k] * p[k];
        __builtin_nontemporal_store(o, &out4[tid + k * stride]);
    }
}

extern "C" void kernel_launch(void* const* d_in, const int* in_sizes, int n_in,
                              void* d_out, int out_size, void* d_ws, size_t ws_size,
                              hipStream_t stream) {
    const float* xs     = (const float*)d_in[0];   // [N, 8] f32
    const int*   idx    = (const int*)d_in[1];     // [N] int32
    const float* params = (const float*)d_in[2];   // [V, 1] f32

    const int n4     = out_size / 4;               // N*D/4 = 8388608
    const int stride = n4 / K_UNROLL;              // 1048576
    const int block  = 256;
    const int grid   = stride / block;             // 4096

    spvar_kernel<<<grid, block, 0, stream>>>(
        (const f4*)xs, idx, params, (f4*)d_out, stride);
}

// Round 3
// 258.395 us; speedup vs baseline: 1.0722x; 1.0722x over previous
//
#include <hip/hip_runtime.h>
#include <hip/hip_bf16.h>

// out[i][d] = params[idx[i]] * xs[i][d];  N=4194304, D=8, V=1048576
// VMEM-request-rate bound. Even-lane-only gather (exec-masked => half the
// gather lane-requests), broadcast to odd partner via __shfl (LDS pipe).

typedef float f4 __attribute__((ext_vector_type(4)));

#define K_UNROLL 8

__global__ __launch_bounds__(256) void spvar_kernel(
    const f4*    __restrict__ xs4,
    const int*   __restrict__ idx,
    const float* __restrict__ params,
    f4*          __restrict__ out4,
    int stride)   // stride = n4 / K_UNROLL; grid*block == stride exactly
{
    const int tid  = blockIdx.x * blockDim.x + threadIdx.x;
    const int lane = threadIdx.x & 63;

    // Even lanes only: idx load + params gather. Odd lanes issue NOTHING,
    // halving gather line-requests (lanes 2k,2k+1 want the same address).
    float p[K_UNROLL];
    if ((lane & 1) == 0) {
        int id[K_UNROLL];
#pragma unroll
        for (int k = 0; k < K_UNROLL; ++k) {
            int i = tid + k * stride;
            id[k] = idx[i >> 1];                  // D=8 -> 2 f4 per row
        }
#pragma unroll
        for (int k = 0; k < K_UNROLL; ++k)
            p[k] = params[id[k]];
    }

    // Streaming xs loads: 8 independent, perfectly coalesced, non-temporal.
    f4 x[K_UNROLL];
#pragma unroll
    for (int k = 0; k < K_UNROLL; ++k)
        x[k] = __builtin_nontemporal_load(&xs4[tid + k * stride]);

    // Broadcast even lane's p to its odd partner (ds_bpermute, no VMEM).
#pragma unroll
    for (int k = 0; k < K_UNROLL; ++k)
        p[k] = __shfl(p[k], lane & ~1);

#pragma unroll
    for (int k = 0; k < K_UNROLL; ++k) {
        f4 o = x[k] * p[k];
        __builtin_nontemporal_store(o, &out4[tid + k * stride]);
    }
}

extern "C" void kernel_launch(void* const* d_in, const int* in_sizes, int n_in,
                              void* d_out, int out_size, void* d_ws, size_t ws_size,
                              hipStream_t stream) {
    const float* xs     = (const float*)d_in[0];   // [N, 8] f32
    const int*   idx    = (const int*)d_in[1];     // [N] int32
    const float* params = (const float*)d_in[2];   // [V, 1] f32

    const int n4     = out_size / 4;               // N*D/4 = 8388608
    const int stride = n4 / K_UNROLL;              // 1048576
    const int block  = 256;
    const int grid   = stride / block;             // 4096

    spvar_kernel<<<grid, block, 0, stream>>>(
        (const f4*)xs, idx, params, (f4*)d_out, stride);
}